// Round 1
// baseline (161.551 us; speedup 1.0000x reference)
//
#include <hip/hip_runtime.h>

// ante[e, i*3+j] = exp(-2*(x1 - c_i)^2) * exp(-2*(x2 - c_j)^2)
// x1 = feat[dst][0] - feat[src][0], x2 = feat[dst][1] - feat[src][1]
// c = {-1, 0, +1}, inv2s2 = 1/(2*0.5^2) = 2.0

__global__ __launch_bounds__(256) void ante_kernel(
    const float* __restrict__ feat,
    const int*   __restrict__ esrc,
    const int*   __restrict__ edst,
    float*       __restrict__ out,
    int e4)  // number of 4-edge groups
{
    int t = blockIdx.x * blockDim.x + threadIdx.x;
    if (t >= e4) return;

    const int4 s4 = reinterpret_cast<const int4*>(esrc)[t];
    const int4 d4 = reinterpret_cast<const int4*>(edst)[t];
    const int ss[4] = {s4.x, s4.y, s4.z, s4.w};
    const int dd[4] = {d4.x, d4.y, d4.z, d4.w};

    float res[36];

#pragma unroll
    for (int q = 0; q < 4; ++q) {
        // feat row stride = 8 floats (32B); coords are dims 0,1 -> aligned float2
        const float2 fs = *reinterpret_cast<const float2*>(feat + (size_t)ss[q] * 8);
        const float2 fd = *reinterpret_cast<const float2*>(feat + (size_t)dd[q] * 8);
        const float x1 = fd.x - fs.x;
        const float x2 = fd.y - fs.y;

        float m1[3], m2[3];
        {
            const float a = x1 + 1.0f, b = x1, c = x1 - 1.0f;
            m1[0] = __expf(-2.0f * a * a);
            m1[1] = __expf(-2.0f * b * b);
            m1[2] = __expf(-2.0f * c * c);
        }
        {
            const float a = x2 + 1.0f, b = x2, c = x2 - 1.0f;
            m2[0] = __expf(-2.0f * a * a);
            m2[1] = __expf(-2.0f * b * b);
            m2[2] = __expf(-2.0f * c * c);
        }
#pragma unroll
        for (int i = 0; i < 3; ++i)
#pragma unroll
            for (int j = 0; j < 3; ++j)
                res[q * 9 + i * 3 + j] = m1[i] * m2[j];
    }

    // 4 edges * 9 floats = 144B contiguous, 16B aligned (t*144 % 16 == 0)
    float4* out4 = reinterpret_cast<float4*>(out) + (size_t)t * 9;
    const float4* r4 = reinterpret_cast<const float4*>(res);
#pragma unroll
    for (int k = 0; k < 9; ++k) out4[k] = r4[k];
}

extern "C" void kernel_launch(void* const* d_in, const int* in_sizes, int n_in,
                              void* d_out, int out_size, void* d_ws, size_t ws_size,
                              hipStream_t stream) {
    const float* feat = (const float*)d_in[0];
    const int*   esrc = (const int*)d_in[1];
    const int*   edst = (const int*)d_in[2];
    // d_in[3] = etypes, unused by the reference output
    float* out = (float*)d_out;

    const int E  = in_sizes[1];      // 6,400,000
    const int e4 = E / 4;            // divisible by 4
    const int block = 256;
    const int grid  = (e4 + block - 1) / block;
    ante_kernel<<<grid, block, 0, stream>>>(feat, esrc, edst, out, e4);
}

// Round 2
// 103.736 us; speedup vs baseline: 1.5573x; 1.5573x over previous
//
#include <hip/hip_runtime.h>

// ante[e, i*3+j] = exp(-2*(x1 - c_i)^2) * exp(-2*(x2 - c_j)^2)
// x1 = feat[dst][0] - feat[src][0], x2 = feat[dst][1] - feat[src][1]
// c = {-1, 0, +1}, 1/(2*sigma^2) = 2.0
//
// R2: LDS store-transpose. Each thread computes 4 consecutive edges (36 floats)
// into LDS (stride 37 dwords -> conflict-free), then the block writes its
// 36864B output span with fully-contiguous per-instruction float4 stores
// (1024B per wave per store instr) to eliminate partial-line write
// amplification + RMW fetches seen in R1 (WRITE 310MB vs 230 ideal,
// FETCH 158MB vs ~80 ideal).

#define TPB 256
#define PAD 37  // 36 dwords per thread, +1 pad

__global__ __launch_bounds__(TPB) void ante_kernel(
    const float* __restrict__ feat,
    const int*   __restrict__ esrc,
    const int*   __restrict__ edst,
    float*       __restrict__ out,
    int e4,      // number of 4-edge groups
    int nf4)     // total output float4 count
{
    __shared__ float lds[TPB * PAD];
    const int tid = threadIdx.x;
    const int t   = blockIdx.x * TPB + tid;

    if (t < e4) {
        const int4 s4 = reinterpret_cast<const int4*>(esrc)[t];
        const int4 d4 = reinterpret_cast<const int4*>(edst)[t];
        const int ss[4] = {s4.x, s4.y, s4.z, s4.w};
        const int dd[4] = {d4.x, d4.y, d4.z, d4.w};
        float* my = &lds[tid * PAD];

#pragma unroll
        for (int q = 0; q < 4; ++q) {
            // feat row stride = 8 floats (32B); coords are dims 0,1 -> aligned float2
            const float2 fs = *reinterpret_cast<const float2*>(feat + (size_t)ss[q] * 8);
            const float2 fd = *reinterpret_cast<const float2*>(feat + (size_t)dd[q] * 8);
            const float x1 = fd.x - fs.x;
            const float x2 = fd.y - fs.y;

            float m1[3], m2[3];
            {
                const float a = x1 + 1.0f, c = x1 - 1.0f;
                m1[0] = __expf(-2.0f * a * a);
                m1[1] = __expf(-2.0f * x1 * x1);
                m1[2] = __expf(-2.0f * c * c);
            }
            {
                const float a = x2 + 1.0f, c = x2 - 1.0f;
                m2[0] = __expf(-2.0f * a * a);
                m2[1] = __expf(-2.0f * x2 * x2);
                m2[2] = __expf(-2.0f * c * c);
            }
#pragma unroll
            for (int i = 0; i < 3; ++i)
#pragma unroll
                for (int j = 0; j < 3; ++j)
                    my[q * 9 + i * 3 + j] = m1[i] * m2[j];
        }
    }
    __syncthreads();

    // Store phase: block's output span is [blk_f4, blk_f4 + 2304) float4s,
    // fully contiguous. Slot f = k*TPB+tid reads thread f/9's dwords.
    const size_t blk_f4 = (size_t)blockIdx.x * (TPB * 9);
    float4* out4 = reinterpret_cast<float4*>(out);

#pragma unroll
    for (int k = 0; k < 9; ++k) {
        const int f = k * TPB + tid;
        const size_t g = blk_f4 + (size_t)f;
        if (g < (size_t)nf4) {
            const int ts = f / 9;          // source thread
            const int r  = f - ts * 9;     // float4 index within its 36 dwords
            const float* p = &lds[ts * PAD + r * 4];
            float4 v;
            v.x = p[0]; v.y = p[1]; v.z = p[2]; v.w = p[3];
            out4[g] = v;
        }
    }
}

extern "C" void kernel_launch(void* const* d_in, const int* in_sizes, int n_in,
                              void* d_out, int out_size, void* d_ws, size_t ws_size,
                              hipStream_t stream) {
    const float* feat = (const float*)d_in[0];
    const int*   esrc = (const int*)d_in[1];
    const int*   edst = (const int*)d_in[2];
    // d_in[3] = etypes, unused by the reference output
    float* out = (float*)d_out;

    const int E   = in_sizes[1];         // 6,400,000
    const int e4  = E / 4;               // 4-edge groups (E divisible by 4)
    const int nf4 = out_size / 4;        // output float4 count
    const int grid = (e4 + TPB - 1) / TPB;
    ante_kernel<<<grid, TPB, 0, stream>>>(feat, esrc, edst, out, e4, nf4);
}

// Round 3
// 97.975 us; speedup vs baseline: 1.6489x; 1.0588x over previous
//
#include <hip/hip_runtime.h>

// ante[e, i*3+j] = exp(-2*(x1 - c_i)^2) * exp(-2*(x2 - c_j)^2)
// x1 = feat[dst][0] - feat[src][0], x2 = feat[dst][1] - feat[src][1]
// c = {-1, 0, +1}, 1/(2*sigma^2) = 2.0
//
// R3: all-b128 LDS transpose. R2 was LDS-pipe-bound (72 scalar ds ops/thread,
// ~66-85% of per-CU cycle budget). Linear float4 LDS layout:
//   write: thread t -> slots 9t..9t+8  (ds_write_b128, bank-group (t+k)%8 uniform)
//   read:  slot k*256+tid              (ds_read_b128, lane-consecutive)
// 18 b128 ops/thread, conflict-free both phases, and the /9 division in the
// store phase is gone (slot index == output float4 index).

#define TPB 256

__global__ __launch_bounds__(TPB) void ante_kernel(
    const float* __restrict__ feat,
    const int*   __restrict__ esrc,
    const int*   __restrict__ edst,
    float*       __restrict__ out,
    int e4,      // number of 4-edge groups
    int nf4)     // total output float4 count
{
    __shared__ float4 lds4[TPB * 9];
    const int tid = threadIdx.x;
    const int t   = blockIdx.x * TPB + tid;

    if (t < e4) {
        const int4 s4 = reinterpret_cast<const int4*>(esrc)[t];
        const int4 d4 = reinterpret_cast<const int4*>(edst)[t];
        const int ss[4] = {s4.x, s4.y, s4.z, s4.w};
        const int dd[4] = {d4.x, d4.y, d4.z, d4.w};

        float res[36];
#pragma unroll
        for (int q = 0; q < 4; ++q) {
            // feat row stride = 8 floats (32B); coords are dims 0,1 -> aligned float2
            const float2 fs = *reinterpret_cast<const float2*>(feat + (size_t)ss[q] * 8);
            const float2 fd = *reinterpret_cast<const float2*>(feat + (size_t)dd[q] * 8);
            const float x1 = fd.x - fs.x;
            const float x2 = fd.y - fs.y;

            float m1[3], m2[3];
            {
                const float a = x1 + 1.0f, c = x1 - 1.0f;
                m1[0] = __expf(-2.0f * a * a);
                m1[1] = __expf(-2.0f * x1 * x1);
                m1[2] = __expf(-2.0f * c * c);
            }
            {
                const float a = x2 + 1.0f, c = x2 - 1.0f;
                m2[0] = __expf(-2.0f * a * a);
                m2[1] = __expf(-2.0f * x2 * x2);
                m2[2] = __expf(-2.0f * c * c);
            }
#pragma unroll
            for (int i = 0; i < 3; ++i)
#pragma unroll
                for (int j = 0; j < 3; ++j)
                    res[q * 9 + i * 3 + j] = m1[i] * m2[j];
        }

        // 9 x ds_write_b128 into own contiguous region (16B-aligned base)
        float4* my4 = &lds4[tid * 9];
#pragma unroll
        for (int k = 0; k < 9; ++k) {
            float4 v;
            v.x = res[k * 4 + 0];
            v.y = res[k * 4 + 1];
            v.z = res[k * 4 + 2];
            v.w = res[k * 4 + 3];
            my4[k] = v;
        }
    }
    __syncthreads();

    // Store phase: slot f = k*TPB+tid is both the LDS index and the output
    // float4 index within this block's span. Lane-consecutive b128 reads,
    // fully contiguous 1024B-per-wave global stores.
    const size_t blk_f4 = (size_t)blockIdx.x * (TPB * 9);
    float4* out4 = reinterpret_cast<float4*>(out);

#pragma unroll
    for (int k = 0; k < 9; ++k) {
        const int f = k * TPB + tid;
        const size_t g = blk_f4 + (size_t)f;
        if (g < (size_t)nf4) out4[g] = lds4[f];
    }
}

extern "C" void kernel_launch(void* const* d_in, const int* in_sizes, int n_in,
                              void* d_out, int out_size, void* d_ws, size_t ws_size,
                              hipStream_t stream) {
    const float* feat = (const float*)d_in[0];
    const int*   esrc = (const int*)d_in[1];
    const int*   edst = (const int*)d_in[2];
    // d_in[3] = etypes, unused by the reference output
    float* out = (float*)d_out;

    const int E   = in_sizes[1];         // 6,400,000
    const int e4  = E / 4;               // 4-edge groups (E divisible by 4)
    const int nf4 = out_size / 4;        // output float4 count
    const int grid = (e4 + TPB - 1) / TPB;
    ante_kernel<<<grid, TPB, 0, stream>>>(feat, esrc, edst, out, e4, nf4);
}

// Round 4
// 97.313 us; speedup vs baseline: 1.6601x; 1.0068x over previous
//
#include <hip/hip_runtime.h>

// ante[e, i*3+j] = exp(-2*(x1 - c_i)^2) * exp(-2*(x2 - c_j)^2)
// x1 = feat[dst][0] - feat[src][0], x2 = feat[dst][1] - feat[src][1]
// c = {-1, 0, +1}, 1/(2*sigma^2) = 2.0
//
// R4: occupancy fix. R3 had 144B LDS/thread (4 edges) -> 4 blocks/CU = 4
// waves/SIMD; the L2-hit gather phase was latency-bound with too few waves.
// Now 2 edges/thread (72B LDS) -> 18.4KB/block -> 8 blocks/CU = 32 waves/CU.
// LDS: write 9 x ds_write_b64 at dword base 18t (bank floor, conflict-free),
// read ds_read_b128 at float4 slot k*256+tid (floor). Non-temporal edge loads
// + output stores keep feat resident in L2 for the gathers.

#define TPB 256

typedef float  f2 __attribute__((ext_vector_type(2)));
typedef float  f4 __attribute__((ext_vector_type(4)));
typedef int    i2 __attribute__((ext_vector_type(2)));

__global__ __launch_bounds__(TPB, 8) void ante_kernel(
    const float* __restrict__ feat,
    const int*   __restrict__ esrc,
    const int*   __restrict__ edst,
    float*       __restrict__ out,
    int e2,      // number of 2-edge groups
    int nf4)     // total output float4 count
{
    __shared__ float lds[TPB * 18];   // 18 KB/block -> 8 blocks/CU
    const int tid = threadIdx.x;
    const int t   = blockIdx.x * TPB + tid;

    if (t < e2) {
        const i2 s2 = __builtin_nontemporal_load(reinterpret_cast<const i2*>(esrc) + t);
        const i2 d2 = __builtin_nontemporal_load(reinterpret_cast<const i2*>(edst) + t);

        // Issue all 4 gathers before any arithmetic (maximize MLP).
        const f2 fs0 = *reinterpret_cast<const f2*>(feat + (size_t)s2.x * 8);
        const f2 fd0 = *reinterpret_cast<const f2*>(feat + (size_t)d2.x * 8);
        const f2 fs1 = *reinterpret_cast<const f2*>(feat + (size_t)s2.y * 8);
        const f2 fd1 = *reinterpret_cast<const f2*>(feat + (size_t)d2.y * 8);

        float res[18];
#pragma unroll
        for (int q = 0; q < 2; ++q) {
            const float x1 = (q == 0) ? (fd0.x - fs0.x) : (fd1.x - fs1.x);
            const float x2 = (q == 0) ? (fd0.y - fs0.y) : (fd1.y - fs1.y);

            float m1[3], m2[3];
            {
                const float a = x1 + 1.0f, c = x1 - 1.0f;
                m1[0] = __expf(-2.0f * a * a);
                m1[1] = __expf(-2.0f * x1 * x1);
                m1[2] = __expf(-2.0f * c * c);
            }
            {
                const float a = x2 + 1.0f, c = x2 - 1.0f;
                m2[0] = __expf(-2.0f * a * a);
                m2[1] = __expf(-2.0f * x2 * x2);
                m2[2] = __expf(-2.0f * c * c);
            }
#pragma unroll
            for (int i = 0; i < 3; ++i)
#pragma unroll
                for (int j = 0; j < 3; ++j)
                    res[q * 9 + i * 3 + j] = m1[i] * m2[j];
        }

        // 9 x ds_write_b64, dword base 18*tid (8B aligned), bank-floor pattern.
        f2* my2 = reinterpret_cast<f2*>(lds) + tid * 9;
#pragma unroll
        for (int k = 0; k < 9; ++k) {
            f2 v; v.x = res[2 * k]; v.y = res[2 * k + 1];
            my2[k] = v;
        }
    }
    __syncthreads();

    // Store phase: float4 slot f = k*TPB+tid is both LDS f4 index and the
    // output f4 index within the block's span (1152 f4 per block).
    const size_t blk_f4 = (size_t)blockIdx.x * (TPB * 9 / 2);
    f4* out4 = reinterpret_cast<f4*>(out);
    const f4* lds4 = reinterpret_cast<const f4*>(lds);

#pragma unroll
    for (int k = 0; k < 5; ++k) {
        const int f = k * TPB + tid;
        if (f < TPB * 9 / 2) {
            const size_t g = blk_f4 + (size_t)f;
            if (g < (size_t)nf4)
                __builtin_nontemporal_store(lds4[f], out4 + g);
        }
    }
}

extern "C" void kernel_launch(void* const* d_in, const int* in_sizes, int n_in,
                              void* d_out, int out_size, void* d_ws, size_t ws_size,
                              hipStream_t stream) {
    const float* feat = (const float*)d_in[0];
    const int*   esrc = (const int*)d_in[1];
    const int*   edst = (const int*)d_in[2];
    // d_in[3] = etypes, unused by the reference output
    float* out = (float*)d_out;

    const int E   = in_sizes[1];         // 6,400,000
    const int e2  = E / 2;               // 2-edge groups (E divisible by 2)
    const int nf4 = out_size / 4;        // output float4 count
    const int grid = (e2 + TPB - 1) / TPB;
    ante_kernel<<<grid, TPB, 0, stream>>>(feat, esrc, edst, out, e2, nf4);
}